// Round 8
// baseline (473.110 us; speedup 1.0000x reference)
//
#include <hip/hip_runtime.h>
#include <math.h>

// Problem constants (fixed by the reference)
constexpr int BSZ = 2;
constexpr int SEQ = 2048;
constexpr int NE  = 2048;   // n_embd
constexpr int NH  = 16;
constexpr int HD  = 128;    // head_dim
constexpr int MROWS = BSZ * SEQ;  // 4096

typedef __bf16 bf16x8 __attribute__((ext_vector_type(8)));
typedef float  f32x4  __attribute__((ext_vector_type(4)));

// ---------------------------------------------------------------------------
// bf16 helpers
// ---------------------------------------------------------------------------
__device__ __forceinline__ unsigned short f2bf(float f) {
    union { float f; unsigned u; } v; v.f = f;
    unsigned r = v.u + 0x7fffu + ((v.u >> 16) & 1u);   // round-to-nearest-even
    return (unsigned short)(r >> 16);
}
__device__ __forceinline__ float bf2f(unsigned short s) {
    union { unsigned u; float f; } v; v.u = ((unsigned)s) << 16; return v.f;
}

// async global->LDS, 16 B per lane; lds ptr must be wave-uniform
__device__ __forceinline__ void load_lds16(const void* g, void* l) {
    __builtin_amdgcn_global_load_lds(
        (const __attribute__((address_space(1))) unsigned int*)g,
        (__attribute__((address_space(3))) unsigned int*)l, 16, 0, 0);
}

// ---------------------------------------------------------------------------
// DPP helpers (ctrl must be a literal -> template parameter).
//   0xB1: quad_perm [1,0,3,2] (lane l <-> l^1)
//   0x4E: quad_perm [2,3,0,1] (lane l <-> l^2)
//   0x124: row_ror:4, 0x128: row_ror:8 (within 16-lane row)
// ---------------------------------------------------------------------------
template <int CTRL>
__device__ __forceinline__ float dpp_mv(float x) {
    int v = __builtin_amdgcn_update_dpp(
        0, __builtin_bit_cast(int, x), CTRL, 0xF, 0xF, true);
    return __builtin_bit_cast(float, v);
}
__device__ __forceinline__ float row16_max(float x) {
    x = fmaxf(x, dpp_mv<0xB1>(x));
    x = fmaxf(x, dpp_mv<0x4E>(x));
    x = fmaxf(x, dpp_mv<0x124>(x));
    x = fmaxf(x, dpp_mv<0x128>(x));
    return x;
}
__device__ __forceinline__ float row16_sum(float x) {
    x += dpp_mv<0xB1>(x);
    x += dpp_mv<0x4E>(x);
    x += dpp_mv<0x124>(x);
    x += dpp_mv<0x128>(x);
    return x;
}

// ---------------------------------------------------------------------------
// Weight transpose + cast (z<4): W[K][N] fp32 -> Wt[N][K] bf16.
// z==4: x fp32 -> bf16 cast (fused; one launch fewer).
// ---------------------------------------------------------------------------
__global__ __launch_bounds__(256) void transpose_cast(const float* __restrict__ xf,
                                                      const float* __restrict__ w0,
                                                      const float* __restrict__ w1,
                                                      const float* __restrict__ w2,
                                                      const float* __restrict__ w3,
                                                      ushort* __restrict__ xb,
                                                      ushort* __restrict__ o0,
                                                      ushort* __restrict__ o1,
                                                      ushort* __restrict__ o2,
                                                      ushort* __restrict__ o3)
{
    if (blockIdx.z == 4) {
        // cast path: 4096 blocks x 256 threads x 8 floats = 8.39M elems
        const int tid = threadIdx.y * 32 + threadIdx.x;
        const size_t i = (((size_t)blockIdx.y * 64 + blockIdx.x) * 256 + tid) * 8;
        float4 v0 = *(const float4*)(xf + i);
        float4 v1 = *(const float4*)(xf + i + 4);
        ushort4 a, b;
        a.x = f2bf(v0.x); a.y = f2bf(v0.y); a.z = f2bf(v0.z); a.w = f2bf(v0.w);
        b.x = f2bf(v1.x); b.y = f2bf(v1.y); b.z = f2bf(v1.z); b.w = f2bf(v1.w);
        *(ushort4*)(xb + i)     = a;
        *(ushort4*)(xb + i + 4) = b;
        return;
    }

    const float* S; ushort* D;
    switch (blockIdx.z) {
        case 0: S = w0; D = o0; break;
        case 1: S = w1; D = o1; break;
        case 2: S = w2; D = o2; break;
        default: S = w3; D = o3; break;
    }
    __shared__ float t[32][33];
    const int tx = threadIdx.x, ty = threadIdx.y;
    const int x0 = blockIdx.x * 32, y0 = blockIdx.y * 32;
#pragma unroll
    for (int i = 0; i < 4; ++i)
        t[ty + i * 8][tx] = S[(size_t)(y0 + ty + i * 8) * NE + x0 + tx];
    __syncthreads();
#pragma unroll
    for (int i = 0; i < 4; ++i)
        D[(size_t)(x0 + ty + i * 8) * NE + y0 + tx] = f2bf(t[tx][ty + i * 8]);
}

// ---------------------------------------------------------------------------
// Fused QKV GEMM + RoPE: C = xb[4096,2048] * W[6144,2048]^T.
// 128x128 tile, BK=64 (halves barrier-drain count vs BK=32; LDS 32 KB,
// still 4 blocks/CU). Both-sides XOR slot swizzle (rule #21): linear LDS
// dest for global_load_lds, inverse-permuted global source col, XOR on the
// ds_read slot -> bank-conflict-free at 128B row stride.
// NO blockIdx swizzle: default round-robin gives n%8 == XCD for all m
// (48 n-blocks/m-row, 48%8==0) -> each XCD caches a fixed 3MB slice of W
// in its L2. (Round-6 chunked swizzle tripled FETCH: 106->372 MB.)
// Epilogue by n-range:
//   mat 0/1 -> RoPE in fp32 on acc (pair partner col^1 = lane r^1 via DPP
//              0xB1; trig via __sinf/__cosf -- inline TRANS ops, NOT the
//              sincosf call that spilled the acc file in r5), bf16 store.
//   mat 2   -> Vt[b][h][d][s] bf16 (per-head transposed V).
// ---------------------------------------------------------------------------
__global__ __launch_bounds__(256) void gemm_qkv(const ushort* __restrict__ A,
                                                const ushort* __restrict__ W,
                                                ushort* __restrict__ Qb,
                                                ushort* __restrict__ Kb,
                                                ushort* __restrict__ Vt)
{
    __shared__ ushort Al[128 * 64];
    __shared__ ushort Bl[128 * 64];

    const int tid  = threadIdx.x;
    const int w    = tid >> 6;
    const int lane = tid & 63;
    const int quad = lane >> 4;
    const int r    = lane & 15;
    const int wm   = w & 1;
    const int wn   = w >> 1;
    const int m0 = blockIdx.y * 128;
    const int n0 = blockIdx.x * 128;      // 0..6143 (global row in stacked W)
    const int K  = NE;

    // staging geometry: thread t covers row srow_j = j*32 + (t>>3), physical
    // 16B slot (t&7); source col is the XOR-inverse so that logical slot s of
    // row rho lands at physical slot s ^ (rho & 7).
    const int srow = tid >> 3;                              // 0..31
    const int scol = ((tid & 7) ^ ((tid >> 3) & 7)) * 8;    // swizzled src col

    f32x4 acc[4][4] = {};

    for (int k0 = 0; k0 < K; k0 += 64) {
#pragma unroll
        for (int j = 0; j < 4; ++j) {
            load_lds16(A + (size_t)(m0 + j * 32 + srow) * K + k0 + scol,
                       &Al[j * 2048 + w * 512]);
            load_lds16(W + (size_t)(n0 + j * 32 + srow) * K + k0 + scol,
                       &Bl[j * 2048 + w * 512]);
        }
        __syncthreads();

#pragma unroll
        for (int kh = 0; kh < 2; ++kh) {
            const int sw = (((kh << 2) + quad) ^ (r & 7)) * 8;  // swizzled read slot
            bf16x8 af[4], bfr[4];
#pragma unroll
            for (int it = 0; it < 4; ++it)
                af[it] = *(const bf16x8*)&Al[(wm * 64 + it * 16 + r) * 64 + sw];
#pragma unroll
            for (int jt = 0; jt < 4; ++jt)
                bfr[jt] = *(const bf16x8*)&Bl[(wn * 64 + jt * 16 + r) * 64 + sw];
#pragma unroll
            for (int it = 0; it < 4; ++it)
#pragma unroll
                for (int jt = 0; jt < 4; ++jt)
                    acc[it][jt] = __builtin_amdgcn_mfma_f32_16x16x32_bf16(
                        af[it], bfr[jt], acc[it][jt], 0, 0, 0);
        }
        __syncthreads();
    }

    const int mat  = n0 >> 11;        // 0=Q,1=K,2=V
    const int ncol = n0 & 2047;       // multiple of 128
    if (mat < 2) {
        ushort* C = mat ? Kb : Qb;
        // ---- fused RoPE (fp32, before the single bf16 round) ----
        float invf[4];
#pragma unroll
        for (int jt = 0; jt < 4; ++jt) {
            const int d = (wn * 64 + jt * 16 + r) & 127;
            invf[jt] = exp2f((float)(d >> 1) * -0.20762050593046014f);
        }
        const float sgn = (r & 1) ? 1.0f : -1.0f;  // even: -x2*sn, odd: +x1*sn
#pragma unroll
        for (int it = 0; it < 4; ++it) {
            const int row = m0 + wm * 64 + it * 16 + quad * 4;
#pragma unroll
            for (int jt = 0; jt < 4; ++jt) {
                const int col = ncol + wn * 64 + jt * 16 + r;
#pragma unroll
                for (int reg = 0; reg < 4; ++reg) {
                    const float self = acc[it][jt][reg];
                    const float part = dpp_mv<0xB1>(self);   // lane r^1 = col^1
                    const int s = (row + reg) & 2047;        // position in seq
                    const float f = (float)s * invf[jt];
                    const float sn = __sinf(f);              // inline v_sin_f32
                    const float cs = __cosf(f);              // inline v_cos_f32
                    const float y = self * cs + sgn * part * sn;
                    C[(size_t)(row + reg) * NE + col] = f2bf(y);
                }
            }
        }
    } else {
#pragma unroll
        for (int it = 0; it < 4; ++it) {
            const int row = m0 + wm * 64 + it * 16 + quad * 4;   // 4-aligned
            const int bb = row >> 11;
            const int s  = row & 2047;
#pragma unroll
            for (int jt = 0; jt < 4; ++jt) {
                const int col = ncol + wn * 64 + jt * 16 + r;
                const int hh = col >> 7;
                const int d  = col & 127;
                ushort4 pk;
                pk.x = f2bf(acc[it][jt][0]); pk.y = f2bf(acc[it][jt][1]);
                pk.z = f2bf(acc[it][jt][2]); pk.w = f2bf(acc[it][jt][3]);
                *(ushort4*)&Vt[((size_t)((bb * NH + hh) * HD + d)) * SEQ + s] = pk;
            }
        }
    }
}

// ---------------------------------------------------------------------------
// Output GEMM: out[4096,2048] f32 = Yb[4096,2048] bf16 * woT[2048,2048]^T
// BK=64 + both-sides XOR swizzle (same as gemm_qkv). No blockIdx swizzle
// (16 n-blocks/m-row, 16%8==0 -> n%8 == XCD invariant holds here too).
// ---------------------------------------------------------------------------
__global__ __launch_bounds__(256) void gemm_out(const ushort* __restrict__ A,
                                                const ushort* __restrict__ Bt,
                                                float* __restrict__ C)
{
    __shared__ ushort Al[128 * 64];
    __shared__ ushort Bl[128 * 64];

    const int tid  = threadIdx.x;
    const int w    = tid >> 6;
    const int lane = tid & 63;
    const int quad = lane >> 4;
    const int r    = lane & 15;
    const int wm   = w & 1;
    const int wn   = w >> 1;
    const int m0 = blockIdx.y * 128;
    const int n0 = blockIdx.x * 128;
    const int K  = NE;

    const int srow = tid >> 3;
    const int scol = ((tid & 7) ^ ((tid >> 3) & 7)) * 8;

    f32x4 acc[4][4] = {};

    for (int k0 = 0; k0 < K; k0 += 64) {
#pragma unroll
        for (int j = 0; j < 4; ++j) {
            load_lds16(A  + (size_t)(m0 + j * 32 + srow) * K + k0 + scol,
                       &Al[j * 2048 + w * 512]);
            load_lds16(Bt + (size_t)(n0 + j * 32 + srow) * K + k0 + scol,
                       &Bl[j * 2048 + w * 512]);
        }
        __syncthreads();

#pragma unroll
        for (int kh = 0; kh < 2; ++kh) {
            const int sw = (((kh << 2) + quad) ^ (r & 7)) * 8;
            bf16x8 af[4], bfr[4];
#pragma unroll
            for (int it = 0; it < 4; ++it)
                af[it] = *(const bf16x8*)&Al[(wm * 64 + it * 16 + r) * 64 + sw];
#pragma unroll
            for (int jt = 0; jt < 4; ++jt)
                bfr[jt] = *(const bf16x8*)&Bl[(wn * 64 + jt * 16 + r) * 64 + sw];
#pragma unroll
            for (int it = 0; it < 4; ++it)
#pragma unroll
                for (int jt = 0; jt < 4; ++jt)
                    acc[it][jt] = __builtin_amdgcn_mfma_f32_16x16x32_bf16(
                        af[it], bfr[jt], acc[it][jt], 0, 0, 0);
        }
        __syncthreads();
    }

#pragma unroll
    for (int it = 0; it < 4; ++it) {
        const int row = m0 + wm * 64 + it * 16 + quad * 4;
#pragma unroll
        for (int jt = 0; jt < 4; ++jt) {
            const int col = n0 + wn * 64 + jt * 16 + r;
#pragma unroll
            for (int reg = 0; reg < 4; ++reg)
                C[(size_t)(row + reg) * NE + col] = acc[it][jt][reg];
        }
    }
}

// ---------------------------------------------------------------------------
// MFMA flash attention, QBLK=128: block = 128 q-rows of one (b,h); 4 waves;
// wave w owns TWO 16-row strips (rows w*16 and 64+w*16), processed
// sequentially against each staged 64-kv K/V tile. Halves K/V HBM fetch and
// doubles MFMA work per stage+barrier vs QBLK=64 (r7: FETCH 125MB, MfmaUtil
// 9.4%). Causal, online softmax per strip. Ps rows are wave-private and
// reused across strips (per-wave in-order LDS FIFO makes the WAR safe).
// All strip arrays statically indexed via fully-unrolled s-loops (rule #20).
//  - Q fragments in registers (LDS 44 KB -> 3 blocks/CU).
//  - DPP softmax reductions; T5 setprio around MFMA clusters.
//  - Direct global->LDS staging (allocator-safe; r1/r2's cross-body reg
//    prefetch spilled and is permanently discarded).
// Spill tripwire: WRITE_SIZE >> 16 MB means acc_o[2][8] overflowed the
// allocator -> revert to QBLK=64.
// ---------------------------------------------------------------------------
__global__ __launch_bounds__(256, 2) void flash_attn(const ushort* __restrict__ Qg,
                                                     const ushort* __restrict__ Kg,
                                                     const ushort* __restrict__ Vtg,
                                                     ushort* __restrict__ Yg)
{
    const int qb = (int)gridDim.x - 1 - (int)blockIdx.x;  // big blocks first
    const int bh = blockIdx.y;
    const int b = bh >> 4, h = bh & 15;
    const int tid  = threadIdx.x;
    const int w    = tid >> 6;
    const int lane = tid & 63;
    const int quad = lane >> 4;
    const int r    = lane & 15;

    __shared__ ushort Ks[64][136];
    __shared__ ushort Vts[128][72];
    __shared__ ushort Ps[64][72];

    const int q0 = qb * 128;
    const size_t qkbase = (size_t)b * SEQ * NE + (size_t)h * HD;
    const size_t vbase  = (size_t)(bh * HD) * SEQ;
    const float scale = 0.088388347648318447f;  // 1/sqrt(128)

    // ---- Q fragments for both strips (registers, loaded once) ----
    bf16x8 aq[2][4];
#pragma unroll
    for (int s = 0; s < 2; ++s) {
        const ushort* qrow = Qg + qkbase + (size_t)(q0 + s * 64 + w * 16 + r) * NE;
#pragma unroll
        for (int kc = 0; kc < 4; ++kc)
            aq[s][kc] = *(const bf16x8*)(qrow + kc * 32 + quad * 8);
    }

    float m_i[2][4], l_i[2][4];
    f32x4 acc_o[2][8];
#pragma unroll
    for (int s = 0; s < 2; ++s)
#pragma unroll
        for (int reg = 0; reg < 4; ++reg) { m_i[s][reg] = -INFINITY; l_i[s][reg] = 0.f; }
#pragma unroll
    for (int s = 0; s < 2; ++s)
#pragma unroll
        for (int dt = 0; dt < 8; ++dt) acc_o[s][dt] = f32x4{0.f, 0.f, 0.f, 0.f};

    const int ntiles = 2 * qb + 2;
    for (int t = 0; t < ntiles; ++t) {
        const int j0 = t * 64;

        // ---- Stage K tile + Vt tile (direct load->LDS; allocator-safe) ----
        {
            const int row0 = tid >> 4;
            const int ch   = (tid & 15) * 8;
#pragma unroll
            for (int i = 0; i < 4; ++i) {
                const int row = i * 16 + row0;
                *(uint4*)&Ks[row][ch] =
                    *(const uint4*)(Kg + qkbase + (size_t)(j0 + row) * NE + ch);
            }
            const int d0  = tid >> 3;
            const int ch2 = (tid & 7) * 8;
#pragma unroll
            for (int i = 0; i < 4; ++i) {
                const int d = i * 32 + d0;
                *(uint4*)&Vts[d][ch2] =
                    *(const uint4*)(Vtg + vbase + (size_t)d * SEQ + j0 + ch2);
            }
        }
        __syncthreads();

#pragma unroll
        for (int s = 0; s < 2; ++s) {
            const int diag = 2 * qb + s;   // diagonal tile index for strip s
            if (t > diag) continue;        // only strip 0 skips (at t = 2qb+1)

            // ---- S = Q K^T (strip: 16q x 64kv) ----
            __builtin_amdgcn_s_setprio(1);
            f32x4 sa[4];
#pragma unroll
            for (int jt = 0; jt < 4; ++jt) {
                f32x4 acc = {0.f, 0.f, 0.f, 0.f};
#pragma unroll
                for (int kc = 0; kc < 4; ++kc) {
                    bf16x8 bk = *(const bf16x8*)&Ks[jt * 16 + r][kc * 32 + quad * 8];
                    acc = __builtin_amdgcn_mfma_f32_16x16x32_bf16(aq[s][kc], bk, acc, 0, 0, 0);
                }
                sa[jt] = acc;
            }
            __builtin_amdgcn_s_setprio(0);

            // ---- scale + causal mask (diag tile only; same in-tile offsets
            //      for both strips since q0+s*64 == diag*64) ----
            if (t == diag) {
#pragma unroll
                for (int jt = 0; jt < 4; ++jt)
#pragma unroll
                    for (int reg = 0; reg < 4; ++reg)
                        sa[jt][reg] = (jt * 16 + r > w * 16 + quad * 4 + reg)
                                      ? -INFINITY : sa[jt][reg] * scale;
            } else {
#pragma unroll
                for (int jt = 0; jt < 4; ++jt)
#pragma unroll
                    for (int reg = 0; reg < 4; ++reg)
                        sa[jt][reg] *= scale;
            }

            // ---- online softmax (row = quad*4+reg; DPP 16-lane reductions) ----
            float rmax[4], alpha[4], rsum[4];
#pragma unroll
            for (int reg = 0; reg < 4; ++reg) {
                rmax[reg] = fmaxf(fmaxf(sa[0][reg], sa[1][reg]),
                                  fmaxf(sa[2][reg], sa[3][reg]));
                rmax[reg] = row16_max(rmax[reg]);
            }

#pragma unroll
            for (int reg = 0; reg < 4; ++reg) {
                const float mnew = fmaxf(m_i[s][reg], rmax[reg]);
                alpha[reg] = __expf(m_i[s][reg] - mnew);
                m_i[s][reg] = mnew;
                rsum[reg] = 0.f;
            }
#pragma unroll
            for (int jt = 0; jt < 4; ++jt)
#pragma unroll
                for (int reg = 0; reg < 4; ++reg) {
                    const float p = __expf(sa[jt][reg] - m_i[s][reg]);
                    sa[jt][reg] = p;
                    rsum[reg] += p;
                }
#pragma unroll
            for (int reg = 0; reg < 4; ++reg) {
                rsum[reg] = row16_sum(rsum[reg]);
                l_i[s][reg] = l_i[s][reg] * alpha[reg] + rsum[reg];
            }

            // ---- P -> LDS (wave-private rows, reused across strips; in-wave
            //      LDS FIFO ordering covers both RAW and the strip-B WAR) ----
#pragma unroll
            for (int jt = 0; jt < 4; ++jt)
#pragma unroll
                for (int reg = 0; reg < 4; ++reg)
                    Ps[w * 16 + quad * 4 + reg][jt * 16 + r] = f2bf(sa[jt][reg]);

            // ---- O = O*alpha + P V ----
#pragma unroll
            for (int dt = 0; dt < 8; ++dt)
#pragma unroll
                for (int reg = 0; reg < 4; ++reg)
                    acc_o[s][dt][reg] *= alpha[reg];

            bf16x8 ap[2];
#pragma unroll
            for (int kc = 0; kc < 2; ++kc)
                ap[kc] = *(const bf16x8*)&Ps[w * 16 + r][kc * 32 + quad * 8];
            __builtin_amdgcn_s_setprio(1);
#pragma unroll
            for (int dt = 0; dt < 8; ++dt)
#pragma unroll
                for (int kc = 0; kc < 2; ++kc) {
                    bf16x8 bv = *(const bf16x8*)&Vts[dt * 16 + r][kc * 32 + quad * 8];
                    acc_o[s][dt] = __builtin_amdgcn_mfma_f32_16x16x32_bf16(
                        ap[kc], bv, acc_o[s][dt], 0, 0, 0);
                }
            __builtin_amdgcn_s_setprio(0);
        }
        __syncthreads();   // protect Ks/Vts before next staging write
    }

    // ---- Epilogue: O /= l, write bf16 (both strips) ----
#pragma unroll
    for (int s = 0; s < 2; ++s)
#pragma unroll
        for (int reg = 0; reg < 4; ++reg) {
            const float inv = 1.0f / l_i[s][reg];
            const size_t rowbase =
                qkbase + (size_t)(q0 + s * 64 + w * 16 + quad * 4 + reg) * NE;
#pragma unroll
            for (int dt = 0; dt < 8; ++dt)
                Yg[rowbase + dt * 16 + r] = f2bf(acc_o[s][dt][reg] * inv);
        }
}

// ---------------------------------------------------------------------------
extern "C" void kernel_launch(void* const* d_in, const int* in_sizes, int n_in,
                              void* d_out, int out_size, void* d_ws, size_t ws_size,
                              hipStream_t stream)
{
    const float* x  = (const float*)d_in[0];
    const float* wq = (const float*)d_in[1];
    const float* wk = (const float*)d_in[2];
    const float* wv = (const float*)d_in[3];
    const float* wo = (const float*)d_in[4];
    float* out = (float*)d_out;

    // ws (bf16 elems): xb | wqT wkT wvT woT | Qb | Kb | Vt   = 96 MiB
    ushort* ws = (ushort*)d_ws;
    const size_t MAT  = (size_t)MROWS * NE;   // 8M
    const size_t WMAT = (size_t)NE * NE;      // 4M
    ushort* xb  = ws;
    ushort* wqT = xb + MAT;
    ushort* wkT = wqT + WMAT;
    ushort* wvT = wkT + WMAT;
    ushort* woT = wvT + WMAT;
    ushort* Qb  = woT + WMAT;
    ushort* Kb  = Qb + MAT;
    ushort* Vt  = Kb + MAT;
    ushort* Yb  = Qb;   // alias, safe (see flash_attn)

    // z<4: transpose+cast the 4 weights; z==4: cast x -> bf16
    transpose_cast<<<dim3(64, 64, 5), dim3(32, 8), 0, stream>>>(
        x, wq, wk, wv, wo, xb, wqT, wkT, wvT, woT);

    // Fused QKV GEMM + RoPE: W = wqT|wkT|wvT stacked (contiguous) = [6144][2048]
    gemm_qkv<<<dim3(48, 32), 256, 0, stream>>>(xb, wqT, Qb, Kb, Vt);

    flash_attn<<<dim3(SEQ / 128, BSZ * NH), 256, 0, stream>>>(Qb, Kb, Vt, Yb);

    gemm_out<<<dim3(16, 32), 256, 0, stream>>>(Yb, woT, out);
}

// Round 9
// 428.931 us; speedup vs baseline: 1.1030x; 1.1030x over previous
//
#include <hip/hip_runtime.h>
#include <math.h>

// Problem constants (fixed by the reference)
constexpr int BSZ = 2;
constexpr int SEQ = 2048;
constexpr int NE  = 2048;   // n_embd
constexpr int NH  = 16;
constexpr int HD  = 128;    // head_dim
constexpr int MROWS = BSZ * SEQ;  // 4096

typedef __bf16 bf16x8 __attribute__((ext_vector_type(8)));
typedef float  f32x4  __attribute__((ext_vector_type(4)));

// ---------------------------------------------------------------------------
// bf16 helpers
// ---------------------------------------------------------------------------
__device__ __forceinline__ unsigned short f2bf(float f) {
    union { float f; unsigned u; } v; v.f = f;
    unsigned r = v.u + 0x7fffu + ((v.u >> 16) & 1u);   // round-to-nearest-even
    return (unsigned short)(r >> 16);
}
__device__ __forceinline__ float bf2f(unsigned short s) {
    union { unsigned u; float f; } v; v.u = ((unsigned)s) << 16; return v.f;
}

// async global->LDS, 16 B per lane; lds ptr must be wave-uniform
__device__ __forceinline__ void load_lds16(const void* g, void* l) {
    __builtin_amdgcn_global_load_lds(
        (const __attribute__((address_space(1))) unsigned int*)g,
        (__attribute__((address_space(3))) unsigned int*)l, 16, 0, 0);
}

// ---------------------------------------------------------------------------
// DPP helpers (ctrl must be a literal -> template parameter).
//   0xB1: quad_perm [1,0,3,2] (lane l <-> l^1)
//   0x4E: quad_perm [2,3,0,1] (lane l <-> l^2)
//   0x124: row_ror:4, 0x128: row_ror:8 (within 16-lane row)
// ---------------------------------------------------------------------------
template <int CTRL>
__device__ __forceinline__ float dpp_mv(float x) {
    int v = __builtin_amdgcn_update_dpp(
        0, __builtin_bit_cast(int, x), CTRL, 0xF, 0xF, true);
    return __builtin_bit_cast(float, v);
}
__device__ __forceinline__ float row16_max(float x) {
    x = fmaxf(x, dpp_mv<0xB1>(x));
    x = fmaxf(x, dpp_mv<0x4E>(x));
    x = fmaxf(x, dpp_mv<0x124>(x));
    x = fmaxf(x, dpp_mv<0x128>(x));
    return x;
}
__device__ __forceinline__ float row16_sum(float x) {
    x += dpp_mv<0xB1>(x);
    x += dpp_mv<0x4E>(x);
    x += dpp_mv<0x124>(x);
    x += dpp_mv<0x128>(x);
    return x;
}

// ---------------------------------------------------------------------------
// Weight transpose + cast (z<4): W[K][N] fp32 -> Wt[N][K] bf16.
// z==4: x fp32 -> bf16 cast (fused; one launch fewer).
// ---------------------------------------------------------------------------
__global__ __launch_bounds__(256) void transpose_cast(const float* __restrict__ xf,
                                                      const float* __restrict__ w0,
                                                      const float* __restrict__ w1,
                                                      const float* __restrict__ w2,
                                                      const float* __restrict__ w3,
                                                      ushort* __restrict__ xb,
                                                      ushort* __restrict__ o0,
                                                      ushort* __restrict__ o1,
                                                      ushort* __restrict__ o2,
                                                      ushort* __restrict__ o3)
{
    if (blockIdx.z == 4) {
        // cast path: 4096 blocks x 256 threads x 8 floats = 8.39M elems
        const int tid = threadIdx.y * 32 + threadIdx.x;
        const size_t i = (((size_t)blockIdx.y * 64 + blockIdx.x) * 256 + tid) * 8;
        float4 v0 = *(const float4*)(xf + i);
        float4 v1 = *(const float4*)(xf + i + 4);
        ushort4 a, b;
        a.x = f2bf(v0.x); a.y = f2bf(v0.y); a.z = f2bf(v0.z); a.w = f2bf(v0.w);
        b.x = f2bf(v1.x); b.y = f2bf(v1.y); b.z = f2bf(v1.z); b.w = f2bf(v1.w);
        *(ushort4*)(xb + i)     = a;
        *(ushort4*)(xb + i + 4) = b;
        return;
    }

    const float* S; ushort* D;
    switch (blockIdx.z) {
        case 0: S = w0; D = o0; break;
        case 1: S = w1; D = o1; break;
        case 2: S = w2; D = o2; break;
        default: S = w3; D = o3; break;
    }
    __shared__ float t[32][33];
    const int tx = threadIdx.x, ty = threadIdx.y;
    const int x0 = blockIdx.x * 32, y0 = blockIdx.y * 32;
#pragma unroll
    for (int i = 0; i < 4; ++i)
        t[ty + i * 8][tx] = S[(size_t)(y0 + ty + i * 8) * NE + x0 + tx];
    __syncthreads();
#pragma unroll
    for (int i = 0; i < 4; ++i)
        D[(size_t)(x0 + ty + i * 8) * NE + y0 + tx] = f2bf(t[tx][ty + i * 8]);
}

// ---------------------------------------------------------------------------
// Fused QKV GEMM + RoPE: C = xb[4096,2048] * W[6144,2048]^T.
// 128x128 tile, BK=64 (halves barrier-drain count vs BK=32; LDS 32 KB,
// still 4 blocks/CU). Both-sides XOR slot swizzle (rule #21): linear LDS
// dest for global_load_lds, inverse-permuted global source col, XOR on the
// ds_read slot -> bank-conflict-free at 128B row stride.
// NO blockIdx swizzle: default round-robin gives n%8 == XCD for all m
// (48 n-blocks/m-row, 48%8==0) -> each XCD caches a fixed 3MB slice of W
// in its L2. (Round-6 chunked swizzle tripled FETCH: 106->372 MB.)
// Epilogue by n-range:
//   mat 0/1 -> RoPE in fp32 on acc (pair partner col^1 = lane r^1 via DPP
//              0xB1; trig via __sinf/__cosf -- inline TRANS ops, NOT the
//              sincosf call that spilled the acc file in r5), bf16 store.
//   mat 2   -> Vt[b][h][d][s] bf16 (per-head transposed V).
// ---------------------------------------------------------------------------
__global__ __launch_bounds__(256) void gemm_qkv(const ushort* __restrict__ A,
                                                const ushort* __restrict__ W,
                                                ushort* __restrict__ Qb,
                                                ushort* __restrict__ Kb,
                                                ushort* __restrict__ Vt)
{
    __shared__ ushort Al[128 * 64];
    __shared__ ushort Bl[128 * 64];

    const int tid  = threadIdx.x;
    const int w    = tid >> 6;
    const int lane = tid & 63;
    const int quad = lane >> 4;
    const int r    = lane & 15;
    const int wm   = w & 1;
    const int wn   = w >> 1;
    const int m0 = blockIdx.y * 128;
    const int n0 = blockIdx.x * 128;      // 0..6143 (global row in stacked W)
    const int K  = NE;

    // staging geometry: thread t covers row srow_j = j*32 + (t>>3), physical
    // 16B slot (t&7); source col is the XOR-inverse so that logical slot s of
    // row rho lands at physical slot s ^ (rho & 7).
    const int srow = tid >> 3;                              // 0..31
    const int scol = ((tid & 7) ^ ((tid >> 3) & 7)) * 8;    // swizzled src col

    f32x4 acc[4][4] = {};

    for (int k0 = 0; k0 < K; k0 += 64) {
#pragma unroll
        for (int j = 0; j < 4; ++j) {
            load_lds16(A + (size_t)(m0 + j * 32 + srow) * K + k0 + scol,
                       &Al[j * 2048 + w * 512]);
            load_lds16(W + (size_t)(n0 + j * 32 + srow) * K + k0 + scol,
                       &Bl[j * 2048 + w * 512]);
        }
        __syncthreads();

#pragma unroll
        for (int kh = 0; kh < 2; ++kh) {
            const int sw = (((kh << 2) + quad) ^ (r & 7)) * 8;  // swizzled read slot
            bf16x8 af[4], bfr[4];
#pragma unroll
            for (int it = 0; it < 4; ++it)
                af[it] = *(const bf16x8*)&Al[(wm * 64 + it * 16 + r) * 64 + sw];
#pragma unroll
            for (int jt = 0; jt < 4; ++jt)
                bfr[jt] = *(const bf16x8*)&Bl[(wn * 64 + jt * 16 + r) * 64 + sw];
#pragma unroll
            for (int it = 0; it < 4; ++it)
#pragma unroll
                for (int jt = 0; jt < 4; ++jt)
                    acc[it][jt] = __builtin_amdgcn_mfma_f32_16x16x32_bf16(
                        af[it], bfr[jt], acc[it][jt], 0, 0, 0);
        }
        __syncthreads();
    }

    const int mat  = n0 >> 11;        // 0=Q,1=K,2=V
    const int ncol = n0 & 2047;       // multiple of 128
    if (mat < 2) {
        ushort* C = mat ? Kb : Qb;
        // ---- fused RoPE (fp32, before the single bf16 round) ----
        float invf[4];
#pragma unroll
        for (int jt = 0; jt < 4; ++jt) {
            const int d = (wn * 64 + jt * 16 + r) & 127;
            invf[jt] = exp2f((float)(d >> 1) * -0.20762050593046014f);
        }
        const float sgn = (r & 1) ? 1.0f : -1.0f;  // even: -x2*sn, odd: +x1*sn
#pragma unroll
        for (int it = 0; it < 4; ++it) {
            const int row = m0 + wm * 64 + it * 16 + quad * 4;
#pragma unroll
            for (int jt = 0; jt < 4; ++jt) {
                const int col = ncol + wn * 64 + jt * 16 + r;
#pragma unroll
                for (int reg = 0; reg < 4; ++reg) {
                    const float self = acc[it][jt][reg];
                    const float part = dpp_mv<0xB1>(self);   // lane r^1 = col^1
                    const int s = (row + reg) & 2047;        // position in seq
                    const float f = (float)s * invf[jt];
                    const float sn = __sinf(f);              // inline v_sin_f32
                    const float cs = __cosf(f);              // inline v_cos_f32
                    const float y = self * cs + sgn * part * sn;
                    C[(size_t)(row + reg) * NE + col] = f2bf(y);
                }
            }
        }
    } else {
#pragma unroll
        for (int it = 0; it < 4; ++it) {
            const int row = m0 + wm * 64 + it * 16 + quad * 4;   // 4-aligned
            const int bb = row >> 11;
            const int s  = row & 2047;
#pragma unroll
            for (int jt = 0; jt < 4; ++jt) {
                const int col = ncol + wn * 64 + jt * 16 + r;
                const int hh = col >> 7;
                const int d  = col & 127;
                ushort4 pk;
                pk.x = f2bf(acc[it][jt][0]); pk.y = f2bf(acc[it][jt][1]);
                pk.z = f2bf(acc[it][jt][2]); pk.w = f2bf(acc[it][jt][3]);
                *(ushort4*)&Vt[((size_t)((bb * NH + hh) * HD + d)) * SEQ + s] = pk;
            }
        }
    }
}

// ---------------------------------------------------------------------------
// Output GEMM: out[4096,2048] f32 = Yb[4096,2048] bf16 * woT[2048,2048]^T
// BK=64 + both-sides XOR swizzle (same as gemm_qkv). No blockIdx swizzle
// (16 n-blocks/m-row, 16%8==0 -> n%8 == XCD invariant holds here too).
// ---------------------------------------------------------------------------
__global__ __launch_bounds__(256) void gemm_out(const ushort* __restrict__ A,
                                                const ushort* __restrict__ Bt,
                                                float* __restrict__ C)
{
    __shared__ ushort Al[128 * 64];
    __shared__ ushort Bl[128 * 64];

    const int tid  = threadIdx.x;
    const int w    = tid >> 6;
    const int lane = tid & 63;
    const int quad = lane >> 4;
    const int r    = lane & 15;
    const int wm   = w & 1;
    const int wn   = w >> 1;
    const int m0 = blockIdx.y * 128;
    const int n0 = blockIdx.x * 128;
    const int K  = NE;

    const int srow = tid >> 3;
    const int scol = ((tid & 7) ^ ((tid >> 3) & 7)) * 8;

    f32x4 acc[4][4] = {};

    for (int k0 = 0; k0 < K; k0 += 64) {
#pragma unroll
        for (int j = 0; j < 4; ++j) {
            load_lds16(A  + (size_t)(m0 + j * 32 + srow) * K + k0 + scol,
                       &Al[j * 2048 + w * 512]);
            load_lds16(Bt + (size_t)(n0 + j * 32 + srow) * K + k0 + scol,
                       &Bl[j * 2048 + w * 512]);
        }
        __syncthreads();

#pragma unroll
        for (int kh = 0; kh < 2; ++kh) {
            const int sw = (((kh << 2) + quad) ^ (r & 7)) * 8;
            bf16x8 af[4], bfr[4];
#pragma unroll
            for (int it = 0; it < 4; ++it)
                af[it] = *(const bf16x8*)&Al[(wm * 64 + it * 16 + r) * 64 + sw];
#pragma unroll
            for (int jt = 0; jt < 4; ++jt)
                bfr[jt] = *(const bf16x8*)&Bl[(wn * 64 + jt * 16 + r) * 64 + sw];
#pragma unroll
            for (int it = 0; it < 4; ++it)
#pragma unroll
                for (int jt = 0; jt < 4; ++jt)
                    acc[it][jt] = __builtin_amdgcn_mfma_f32_16x16x32_bf16(
                        af[it], bfr[jt], acc[it][jt], 0, 0, 0);
        }
        __syncthreads();
    }

#pragma unroll
    for (int it = 0; it < 4; ++it) {
        const int row = m0 + wm * 64 + it * 16 + quad * 4;
#pragma unroll
        for (int jt = 0; jt < 4; ++jt) {
            const int col = n0 + wn * 64 + jt * 16 + r;
#pragma unroll
            for (int reg = 0; reg < 4; ++reg)
                C[(size_t)(row + reg) * NE + col] = acc[it][jt][reg];
        }
    }
}

// ---------------------------------------------------------------------------
// MFMA flash attention — QBLK=64 (r8's QBLK=128 regressed: grid halved to
// 2 blocks/CU, strips serialized; reverted). r7 structure + unpadded LDS
// with both-sides XOR slot swizzle: reg-staged writes go to physical slot
// (logical_slot ^ (row&7)), reads XOR the same way. LDS 44.6 -> 40.0 KB
// -> 4 blocks/CU (was 3). Block = 64 q-rows of one (b,h); 4 waves; wave w
// owns q strip [w*16,w*16+16); K/V tiles of 64 kv; causal online softmax.
//  - Q fragments in registers; DPP softmax reductions; setprio on MFMA.
//  - Direct global->LDS staging (allocator-safe; cross-body reg prefetch
//    spilled in r1/r2 and is permanently discarded).
// ---------------------------------------------------------------------------
__global__ __launch_bounds__(256, 2) void flash_attn(const ushort* __restrict__ Qg,
                                                     const ushort* __restrict__ Kg,
                                                     const ushort* __restrict__ Vtg,
                                                     ushort* __restrict__ Yg)
{
    const int qt = (int)gridDim.x - 1 - (int)blockIdx.x;  // big blocks first
    const int bh = blockIdx.y;
    const int b = bh >> 4, h = bh & 15;
    const int tid  = threadIdx.x;
    const int w    = tid >> 6;
    const int lane = tid & 63;
    const int quad = lane >> 4;
    const int r    = lane & 15;

    __shared__ ushort Ks[64][128];    // XOR-swizzled, 16 slots/row
    __shared__ ushort Vts[128][64];   // XOR-swizzled, 8 slots/row
    __shared__ ushort Ps[64][64];     // XOR-swizzled, 8 slots/row

    const int q0 = qt * 64;
    const size_t qkbase = (size_t)b * SEQ * NE + (size_t)h * HD;
    const size_t vbase  = (size_t)(bh * HD) * SEQ;
    const float scale = 0.088388347648318447f;  // 1/sqrt(128)

    bf16x8 aq[4];
    {
        const ushort* qrow = Qg + qkbase + (size_t)(q0 + w * 16 + r) * NE;
#pragma unroll
        for (int kc = 0; kc < 4; ++kc)
            aq[kc] = *(const bf16x8*)(qrow + kc * 32 + quad * 8);
    }

    float m_i[4], l_i[4];
    f32x4 acc_o[8];
#pragma unroll
    for (int reg = 0; reg < 4; ++reg) { m_i[reg] = -INFINITY; l_i[reg] = 0.f; }
#pragma unroll
    for (int dt = 0; dt < 8; ++dt) acc_o[dt] = f32x4{0.f, 0.f, 0.f, 0.f};

    const int rx = r & 7;   // row&7 for all read rows (row = *.16 + r)

    for (int t = 0; t <= qt; ++t) {
        const int j0 = t * 64;

        // ---- Stage K + Vt (reg-staged; store to XOR-swizzled slot) ----
        {
            const int row0 = tid >> 4;            // 0..15
            const int ks   = tid & 15;            // logical 16B slot in K row
#pragma unroll
            for (int i = 0; i < 4; ++i) {
                const int row = i * 16 + row0;
                *(uint4*)&Ks[row][(ks ^ (row & 7)) * 8] =
                    *(const uint4*)(Kg + qkbase + (size_t)(j0 + row) * NE + ks * 8);
            }
            const int d0 = tid >> 3;              // 0..31
            const int vs = tid & 7;               // logical slot in V row
#pragma unroll
            for (int i = 0; i < 4; ++i) {
                const int d = i * 32 + d0;
                *(uint4*)&Vts[d][(vs ^ (d & 7)) * 8] =
                    *(const uint4*)(Vtg + vbase + (size_t)d * SEQ + j0 + vs * 8);
            }
        }
        __syncthreads();

        // ---- S = Q K^T (wave strip: 16q x 64kv) ----
        __builtin_amdgcn_s_setprio(1);
        f32x4 sa[4];
#pragma unroll
        for (int jt = 0; jt < 4; ++jt) {
            f32x4 acc = {0.f, 0.f, 0.f, 0.f};
#pragma unroll
            for (int kc = 0; kc < 4; ++kc) {
                bf16x8 bk = *(const bf16x8*)&Ks[jt * 16 + r][((kc * 4 + quad) ^ rx) * 8];
                acc = __builtin_amdgcn_mfma_f32_16x16x32_bf16(aq[kc], bk, acc, 0, 0, 0);
            }
            sa[jt] = acc;
        }
        __builtin_amdgcn_s_setprio(0);

        if (t == qt) {
#pragma unroll
            for (int jt = 0; jt < 4; ++jt)
#pragma unroll
                for (int reg = 0; reg < 4; ++reg)
                    sa[jt][reg] = (jt * 16 + r > w * 16 + quad * 4 + reg)
                                  ? -INFINITY : sa[jt][reg] * scale;
        } else {
#pragma unroll
            for (int jt = 0; jt < 4; ++jt)
#pragma unroll
                for (int reg = 0; reg < 4; ++reg)
                    sa[jt][reg] *= scale;
        }

        float rmax[4], alpha[4], rsum[4];
#pragma unroll
        for (int reg = 0; reg < 4; ++reg) {
            rmax[reg] = fmaxf(fmaxf(sa[0][reg], sa[1][reg]),
                              fmaxf(sa[2][reg], sa[3][reg]));
            rmax[reg] = row16_max(rmax[reg]);
        }

#pragma unroll
        for (int reg = 0; reg < 4; ++reg) {
            const float mnew = fmaxf(m_i[reg], rmax[reg]);
            alpha[reg] = __expf(m_i[reg] - mnew);
            m_i[reg] = mnew;
            rsum[reg] = 0.f;
        }
#pragma unroll
        for (int jt = 0; jt < 4; ++jt)
#pragma unroll
            for (int reg = 0; reg < 4; ++reg) {
                const float p = __expf(sa[jt][reg] - m_i[reg]);
                sa[jt][reg] = p;
                rsum[reg] += p;
            }
#pragma unroll
        for (int reg = 0; reg < 4; ++reg) {
            rsum[reg] = row16_sum(rsum[reg]);
            l_i[reg] = l_i[reg] * alpha[reg] + rsum[reg];
        }

        // ---- P -> LDS (wave-private rows; swizzled scalar stores) ----
#pragma unroll
        for (int jt = 0; jt < 4; ++jt)
#pragma unroll
            for (int reg = 0; reg < 4; ++reg) {
                const int prow = w * 16 + quad * 4 + reg;
                const int pcol = jt * 16 + r;
                Ps[prow][((((pcol >> 3) ^ (prow & 7)) << 3) | (pcol & 7))]
                    = f2bf(sa[jt][reg]);
            }

        // ---- O = O*alpha + P V ----
#pragma unroll
        for (int dt = 0; dt < 8; ++dt)
#pragma unroll
            for (int reg = 0; reg < 4; ++reg)
                acc_o[dt][reg] *= alpha[reg];

        bf16x8 ap[2];
#pragma unroll
        for (int kc = 0; kc < 2; ++kc)
            ap[kc] = *(const bf16x8*)&Ps[w * 16 + r][((kc * 4 + quad) ^ rx) * 8];
        __builtin_amdgcn_s_setprio(1);
#pragma unroll
        for (int dt = 0; dt < 8; ++dt)
#pragma unroll
            for (int kc = 0; kc < 2; ++kc) {
                bf16x8 bv = *(const bf16x8*)&Vts[dt * 16 + r][((kc * 4 + quad) ^ rx) * 8];
                acc_o[dt] = __builtin_amdgcn_mfma_f32_16x16x32_bf16(ap[kc], bv, acc_o[dt], 0, 0, 0);
            }
        __builtin_amdgcn_s_setprio(0);
        __syncthreads();   // protect Ks/Vts before next staging write
    }

    // ---- Epilogue: O /= l, write bf16 ----
#pragma unroll
    for (int reg = 0; reg < 4; ++reg) {
        const float inv = 1.0f / l_i[reg];
        const size_t rowbase = qkbase + (size_t)(q0 + w * 16 + quad * 4 + reg) * NE;
#pragma unroll
        for (int dt = 0; dt < 8; ++dt)
            Yg[rowbase + dt * 16 + r] = f2bf(acc_o[dt][reg] * inv);
    }
}

// ---------------------------------------------------------------------------
extern "C" void kernel_launch(void* const* d_in, const int* in_sizes, int n_in,
                              void* d_out, int out_size, void* d_ws, size_t ws_size,
                              hipStream_t stream)
{
    const float* x  = (const float*)d_in[0];
    const float* wq = (const float*)d_in[1];
    const float* wk = (const float*)d_in[2];
    const float* wv = (const float*)d_in[3];
    const float* wo = (const float*)d_in[4];
    float* out = (float*)d_out;

    // ws (bf16 elems): xb | wqT wkT wvT woT | Qb | Kb | Vt   = 96 MiB
    ushort* ws = (ushort*)d_ws;
    const size_t MAT  = (size_t)MROWS * NE;   // 8M
    const size_t WMAT = (size_t)NE * NE;      // 4M
    ushort* xb  = ws;
    ushort* wqT = xb + MAT;
    ushort* wkT = wqT + WMAT;
    ushort* wvT = wkT + WMAT;
    ushort* woT = wvT + WMAT;
    ushort* Qb  = woT + WMAT;
    ushort* Kb  = Qb + MAT;
    ushort* Vt  = Kb + MAT;
    ushort* Yb  = Qb;   // alias, safe (see flash_attn)

    // z<4: transpose+cast the 4 weights; z==4: cast x -> bf16
    transpose_cast<<<dim3(64, 64, 5), dim3(32, 8), 0, stream>>>(
        x, wq, wk, wv, wo, xb, wqT, wkT, wvT, woT);

    // Fused QKV GEMM + RoPE: W = wqT|wkT|wvT stacked (contiguous) = [6144][2048]
    gemm_qkv<<<dim3(48, 32), 256, 0, stream>>>(xb, wqT, Qb, Kb, Vt);

    flash_attn<<<dim3(SEQ / 64, BSZ * NH), 256, 0, stream>>>(Qb, Kb, Vt, Yb);

    gemm_out<<<dim3(16, 32), 256, 0, stream>>>(Yb, woT, out);
}